// Round 13
// baseline (533.273 us; speedup 1.0000x reference)
//
#include <hip/hip_runtime.h>
#include <stdint.h>

#define F_IN 512
#define HF 256
#define OUT_F 2
#define BN_EPS 1e-5f
#define SCAN_B 256
#define LDSTR 36    // LDS row stride (shorts): 0 bank conflicts (measured R7)

typedef __attribute__((ext_vector_type(8))) short bf16x8;
typedef __attribute__((ext_vector_type(4))) float f32x4;

__device__ inline float bf2f(unsigned short u) {
    union { float f; uint32_t i; } v; v.i = ((uint32_t)u) << 16; return v.f;
}
__device__ inline unsigned short f2bf(float f) {
    union { float f; uint32_t i; } v; v.f = f;
    uint32_t r = v.i + 0x7FFFu + ((v.i >> 16) & 1u);   // RNE (finite values only)
    return (unsigned short)(r >> 16);
}

// ---------- count atomics + x->bf16 + W transposes + pad zero (all independent) ----------
__global__ void count_conv_kernel(const int* __restrict__ col,
                                  const float* __restrict__ w,
                                  unsigned long long* __restrict__ packed,   // pre-zeroed
                                  const float* __restrict__ x,
                                  unsigned short* __restrict__ xbf,
                                  const float* __restrict__ W1, unsigned short* __restrict__ W1t,
                                  const float* __restrict__ W2, unsigned short* __restrict__ W2t,
                                  unsigned short* __restrict__ xbf_pad,
                                  unsigned short* __restrict__ bufa_pad,
                                  int e, int nchunk, int padx, int pada) {
    int tid = blockIdx.x * blockDim.x + threadIdx.x;
    const int stride = gridDim.x * blockDim.x;
    if (tid < e) {
        unsigned long long add = (1ULL << 40)
            | (unsigned long long)__float2uint_rn(w[tid] * 1048576.0f);
        atomicAdd(&packed[col[tid]], add);
    }
    // x: fp32 -> bf16, 8 elems per chunk (streams under atomic latency)
    const float4* x4 = (const float4*)x;
    for (int c = tid; c < nchunk; c += stride) {
        float4 f0 = x4[2 * c];
        float4 f1 = x4[2 * c + 1];
        bf16x8 v;
        v[0] = (short)f2bf(f0.x); v[1] = (short)f2bf(f0.y);
        v[2] = (short)f2bf(f0.z); v[3] = (short)f2bf(f0.w);
        v[4] = (short)f2bf(f1.x); v[5] = (short)f2bf(f1.y);
        v[6] = (short)f2bf(f1.z); v[7] = (short)f2bf(f1.w);
        *(bf16x8*)(xbf + (size_t)c * 8) = v;
    }
    // weight transposes (bf16, [n][k] layout)
    for (int j = tid; j < F_IN * HF; j += stride) {
        int nn = j >> 9, k = j & (F_IN - 1);
        W1t[j] = f2bf(W1[(size_t)k * HF + nn]);
    }
    for (int j = tid; j < HF * HF; j += stride) {
        int nn = j >> 8, k = j & (HF - 1);
        W2t[j] = f2bf(W2[(size_t)k * HF + nn]);
    }
    for (int j = tid; j < padx; j += stride) xbf_pad[j] = 0;
    for (int j = tid; j < pada; j += stride) bufa_pad[j] = 0;
}

// ---------- scan1: block-local exclusive scan of counts ----------
__global__ void scan1_kernel(const unsigned long long* __restrict__ packed,
                             int* __restrict__ local, int* __restrict__ blocksum, int n) {
    __shared__ int tmp[SCAN_B];
    int i = blockIdx.x * SCAN_B + threadIdx.x;
    int v = (i < n) ? (int)(packed[i] >> 40) : 0;
    tmp[threadIdx.x] = v;
    __syncthreads();
    for (int off = 1; off < SCAN_B; off <<= 1) {
        int t = 0;
        if ((int)threadIdx.x >= off) t = tmp[threadIdx.x - off];
        __syncthreads();
        if ((int)threadIdx.x >= off) tmp[threadIdx.x] += t;
        __syncthreads();
    }
    if (i < n) local[i] = tmp[threadIdx.x] - v;       // exclusive
    if (threadIdx.x == SCAN_B - 1) blocksum[blockIdx.x] = tmp[SCAN_B - 1];
}

// ---------- scan3: add block prefix (re-reduced in-block) + dinv (self-loop folded) ----------
__global__ void scan3_dinv_kernel(int* __restrict__ csr_ptr, int* __restrict__ cursor,
                                  const int* __restrict__ blocksum,
                                  const unsigned long long* __restrict__ packed,
                                  float* __restrict__ dinv, int n, int e, int nb) {
    __shared__ int red[SCAN_B];
    int t = threadIdx.x;
    red[t] = (t < nb && t < (int)blockIdx.x) ? blocksum[t] : 0;
    __syncthreads();
    for (int off = SCAN_B / 2; off > 0; off >>= 1) {
        if (t < off) red[t] += red[t + off];
        __syncthreads();
    }
    int prefix = red[0];
    int i = blockIdx.x * SCAN_B + t;
    if (i < n) {
        int val = csr_ptr[i] + prefix;
        csr_ptr[i] = val;
        cursor[i] = val;
        float deg = 1.0f + (float)(packed[i] & 0xFFFFFFFFFFULL) * (1.0f / 1048576.0f);
        dinv[i] = rsqrtf(deg);   // deg >= 1 always (self-loop)
    }
    if (i == 0) csr_ptr[n] = e;
}

// ---------- pipelined bf16 GEMM body (R10-verified structure) ----------
// BM=BN=128, BK=32; reg prefetch + LDS dbuf, ONE barrier per K-step.
__device__ __forceinline__
void gemm_body(const unsigned short* __restrict__ A,
               const unsigned short* __restrict__ Bt,
               unsigned short* __restrict__ C, int K, int mblk, int nblk,
               unsigned short (*As)[128 * LDSTR], unsigned short (*Bs)[128 * LDSTR]) {
    const int tid  = threadIdx.x;
    const int lane = tid & 63;
    const int wv   = tid >> 6;
    const int wrow = wv >> 1, wcol = wv & 1;
    const int m0 = mblk * 128;
    const int n0 = nblk * 128;

    const int sr = tid >> 2;
    const int sc = (tid & 3) * 8;

    const unsigned short* pa0 = A + (size_t)(m0 + sr) * K + sc;
    const unsigned short* pa1 = A + (size_t)(m0 + sr + 64) * K + sc;
    const unsigned short* pb0 = Bt + (size_t)(n0 + sr) * K + sc;
    const unsigned short* pb1 = Bt + (size_t)(n0 + sr + 64) * K + sc;

    f32x4 zero4 = {0.0f, 0.0f, 0.0f, 0.0f};
    f32x4 acc[4][4];
    #pragma unroll
    for (int i = 0; i < 4; ++i)
        #pragma unroll
        for (int j = 0; j < 4; ++j) acc[i][j] = zero4;

    const int q8 = (lane >> 4) * 8;
    const int ml = lane & 15;

    bf16x8 va0 = *(const bf16x8*)pa0;
    bf16x8 va1 = *(const bf16x8*)pa1;
    bf16x8 vb0 = *(const bf16x8*)pb0;
    bf16x8 vb1 = *(const bf16x8*)pb1;

    const int nsteps = K >> 5;
    for (int s = 0; s < nsteps; ++s) {
        const int buf = s & 1;
        *(bf16x8*)&As[buf][sr * LDSTR + sc]        = va0;
        *(bf16x8*)&As[buf][(sr + 64) * LDSTR + sc] = va1;
        *(bf16x8*)&Bs[buf][sr * LDSTR + sc]        = vb0;
        *(bf16x8*)&Bs[buf][(sr + 64) * LDSTR + sc] = vb1;
        __syncthreads();
        if (s + 1 < nsteps) {
            int off = (s + 1) * 32;
            va0 = *(const bf16x8*)(pa0 + off);
            va1 = *(const bf16x8*)(pa1 + off);
            vb0 = *(const bf16x8*)(pb0 + off);
            vb1 = *(const bf16x8*)(pb1 + off);
        }
        bf16x8 af[4], bfr[4];
        #pragma unroll
        for (int i = 0; i < 4; ++i)
            af[i] = *(const bf16x8*)&As[buf][(wrow * 64 + i * 16 + ml) * LDSTR + q8];
        #pragma unroll
        for (int j = 0; j < 4; ++j)
            bfr[j] = *(const bf16x8*)&Bs[buf][(wcol * 64 + j * 16 + ml) * LDSTR + q8];
        #pragma unroll
        for (int i = 0; i < 4; ++i)
            #pragma unroll
            for (int j = 0; j < 4; ++j)
                acc[i][j] = __builtin_amdgcn_mfma_f32_16x16x32_bf16(af[i], bfr[j], acc[i][j], 0, 0, 0);
    }

    const int q4 = (lane >> 4) * 4;
    #pragma unroll
    for (int i = 0; i < 4; ++i) {
        #pragma unroll
        for (int j = 0; j < 4; ++j) {
            #pragma unroll
            for (int rg = 0; rg < 4; ++rg) {
                int r = m0 + wrow * 64 + i * 16 + q4 + rg;
                int c = n0 + wcol * 64 + j * 16 + ml;
                C[(size_t)r * HF + c] = f2bf(acc[i][j][rg]);
            }
        }
    }
}

// ---------- fused: CSR fill (blocks < nfill, latency-bound) + GEMM1 (compute) ----------
// fill <- scan3 (cursor,dinv); GEMM1 <- count_conv (xbf,W1t): independent of each other.
__global__ __launch_bounds__(256)
void fill_gemm1_kernel(const int* __restrict__ row, const int* __restrict__ col,
                       const float* __restrict__ w, const float* __restrict__ dinv,
                       int* __restrict__ cursor, int2* __restrict__ csr_edge, int e,
                       const unsigned short* __restrict__ A,
                       const unsigned short* __restrict__ Bt,
                       unsigned short* __restrict__ C, int nfill) {
    __shared__ unsigned short As[2][128 * LDSTR];
    __shared__ unsigned short Bs[2][128 * LDSTR];
    int bid = blockIdx.x;
    if (bid < nfill) {
        int i = bid * 256 + (int)threadIdx.x;
        if (i < e) {
            int r = row[i], c = col[i];
            int pos = atomicAdd(&cursor[c], 1);
            float nrm = dinv[r] * w[i] * dinv[c];
            csr_edge[pos] = make_int2(r, __float_as_int(nrm));
        }
    } else {
        int gb = bid - nfill;
        gemm_body(A, Bt, C, F_IN, gb >> 1, gb & 1, As, Bs);
    }
}

// ---------- standalone GEMM (layer 2) ----------
__global__ __launch_bounds__(256)
void gemm_kernel(const unsigned short* __restrict__ A,
                 const unsigned short* __restrict__ Bt,
                 unsigned short* __restrict__ C, int K) {
    __shared__ unsigned short As[2][128 * LDSTR];
    __shared__ unsigned short Bs[2][128 * LDSTR];
    gemm_body(A, Bt, C, K, blockIdx.x, blockIdx.y, As, Bs);
}

// ---------- fused CSR gather + self-loop + bias + BN + ReLU (R12 pipeline) ----------
template<int FINAL>
__global__ void agg_kernel(const unsigned short* __restrict__ h,
                           const int* __restrict__ ptr,
                           const int2* __restrict__ edge,
                           const float* __restrict__ dinv,
                           const float* __restrict__ b, const float* __restrict__ g,
                           const float* __restrict__ be, const float* __restrict__ m,
                           const float* __restrict__ v,
                           unsigned short* __restrict__ out,
                           const float* __restrict__ W3, float* __restrict__ h3, int n) {
    int wid  = (blockIdx.x * blockDim.x + threadIdx.x) >> 6;
    int lane = threadIdx.x & 63;
    if (wid >= n) return;
    int p0 = ptr[wid], p1 = ptr[wid + 1];
    const int fo = lane * 4;
    float a0 = 0.f, a1 = 0.f, a2 = 0.f, a3 = 0.f;

    const int cnt = p1 - p0;
    const int nb  = cnt >> 3;       // full batches of 8

    int2 edC[8], edN[8];
    ushort4 hvC[8];

    if (nb > 0) {
        #pragma unroll
        for (int k = 0; k < 8; ++k) edC[k] = edge[p0 + k];
        if (nb > 1) {
            #pragma unroll
            for (int k = 0; k < 8; ++k) edN[k] = edge[p0 + 8 + k];
        }
        #pragma unroll
        for (int k = 0; k < 8; ++k)
            hvC[k] = *(const ushort4*)(h + (size_t)edC[k].x * HF + fo);

        for (int bb = 0; bb < nb; ++bb) {
            ushort4 hvN[8];
            int2 edN2[8];
            if (bb + 1 < nb) {
                if (bb + 2 < nb) {
                    int pp = p0 + (bb + 2) * 8;
                    #pragma unroll
                    for (int k = 0; k < 8; ++k) edN2[k] = edge[pp + k];
                }
                #pragma unroll
                for (int k = 0; k < 8; ++k)
                    hvN[k] = *(const ushort4*)(h + (size_t)edN[k].x * HF + fo);
            }
            #pragma unroll
            for (int k = 0; k < 8; ++k) {
                float nw = __int_as_float(edC[k].y);
                a0 += nw * bf2f(hvC[k].x);
                a1 += nw * bf2f(hvC[k].y);
                a2 += nw * bf2f(hvC[k].z);
                a3 += nw * bf2f(hvC[k].w);
            }
            #pragma unroll
            for (int k = 0; k < 8; ++k) { edC[k] = edN[k]; edN[k] = edN2[k]; hvC[k] = hvN[k]; }
        }
    }
    const int pend = p0 + nb * 8;
    if (pend < p1) {
        int2 ed[8];
        float wv[8];
        #pragma unroll
        for (int k = 0; k < 8; ++k) {
            int idx = pend + k < p1 ? pend + k : p1 - 1;
            ed[k] = edge[idx];
            wv[k] = (pend + k < p1) ? __int_as_float(ed[k].y) : 0.0f;
        }
        ushort4 hv[8];
        #pragma unroll
        for (int k = 0; k < 8; ++k)
            hv[k] = *(const ushort4*)(h + (size_t)ed[k].x * HF + fo);
        #pragma unroll
        for (int k = 0; k < 8; ++k) {
            a0 += wv[k] * bf2f(hv[k].x);
            a1 += wv[k] * bf2f(hv[k].y);
            a2 += wv[k] * bf2f(hv[k].z);
            a3 += wv[k] * bf2f(hv[k].w);
        }
    }
    // self loop: weight 1, norm = dinv^2
    float s = dinv[wid];
    float sl = s * s;
    ushort4 hv = *(const ushort4*)(h + (size_t)wid * HF + fo);
    a0 += sl * bf2f(hv.x);
    a1 += sl * bf2f(hv.y);
    a2 += sl * bf2f(hv.z);
    a3 += sl * bf2f(hv.w);

    float4 bb  = *(const float4*)(b + fo);
    float4 gg  = *(const float4*)(g + fo);
    float4 bee = *(const float4*)(be + fo);
    float4 mm  = *(const float4*)(m + fo);
    float4 vv  = *(const float4*)(v + fo);
    float f0 = fmaxf((a0 + bb.x - mm.x) * rsqrtf(vv.x + BN_EPS) * gg.x + bee.x, 0.f);
    float f1 = fmaxf((a1 + bb.y - mm.y) * rsqrtf(vv.y + BN_EPS) * gg.y + bee.y, 0.f);
    float f2 = fmaxf((a2 + bb.z - mm.z) * rsqrtf(vv.z + BN_EPS) * gg.z + bee.z, 0.f);
    float f3 = fmaxf((a3 + bb.w - mm.w) * rsqrtf(vv.w + BN_EPS) * gg.w + bee.w, 0.f);

    if (!FINAL) {
        ushort4 o;
        o.x = f2bf(f0); o.y = f2bf(f1); o.z = f2bf(f2); o.w = f2bf(f3);
        *(ushort4*)(out + (size_t)wid * HF + fo) = o;
    } else {
        float4 w0 = *(const float4*)(W3 + fo * 2);
        float4 w1 = *(const float4*)(W3 + fo * 2 + 4);
        float s0 = f0 * w0.x + f1 * w0.z + f2 * w1.x + f3 * w1.z;
        float s1 = f0 * w0.y + f1 * w0.w + f2 * w1.y + f3 * w1.w;
        #pragma unroll
        for (int o = 32; o > 0; o >>= 1) {
            s0 += __shfl_down(s0, o, 64);
            s1 += __shfl_down(s1, o, 64);
        }
        if (lane == 0) {
            h3[wid * 2 + 0] = s0;
            h3[wid * 2 + 1] = s1;
        }
    }
}

// ---------- final: CSR gather (2 features) + self-loop + bias ----------
__global__ void out_kernel(const float* __restrict__ h3,
                           const int* __restrict__ ptr, const int2* __restrict__ edge,
                           const float* __restrict__ dinv,
                           const float* __restrict__ b3, float* __restrict__ out, int n) {
    int i = blockIdx.x * blockDim.x + threadIdx.x;
    if (i >= n) return;
    int p0 = ptr[i], p1 = ptr[i + 1];
    float a0 = 0.f, a1 = 0.f;
    for (int p = p0; p < p1; p += 4) {
        #pragma unroll
        for (int k = 0; k < 4; ++k) {
            int idx = p + k < p1 ? p + k : p1 - 1;
            int2 e = edge[idx];
            float nw = (p + k < p1) ? __int_as_float(e.y) : 0.0f;
            float2 u = *(const float2*)(h3 + 2 * e.x);
            a0 += nw * u.x;
            a1 += nw * u.y;
        }
    }
    float s = dinv[i];
    float sl = s * s;
    out[2 * i + 0] = a0 + sl * h3[2 * i + 0] + b3[0];
    out[2 * i + 1] = a1 + sl * h3[2 * i + 1] + b3[1];
}

static inline char* align16(char* p) {
    return (char*)(((uintptr_t)p + 15) & ~(uintptr_t)15);
}

extern "C" void kernel_launch(void* const* d_in, const int* in_sizes, int n_in,
                              void* d_out, int out_size, void* d_ws, size_t ws_size,
                              hipStream_t stream) {
    const float* x   = (const float*)d_in[0];
    const int*   ei  = (const int*)d_in[1];    // int64 in reference -> int32 in harness
    const float* ew  = (const float*)d_in[2];
    const float* W1  = (const float*)d_in[3];
    const float* b1  = (const float*)d_in[4];
    const float* g1  = (const float*)d_in[5];
    const float* be1 = (const float*)d_in[6];
    const float* m1  = (const float*)d_in[7];
    const float* v1  = (const float*)d_in[8];
    const float* W2  = (const float*)d_in[9];
    const float* b2  = (const float*)d_in[10];
    const float* g2  = (const float*)d_in[11];
    const float* be2 = (const float*)d_in[12];
    const float* m2  = (const float*)d_in[13];
    const float* v2  = (const float*)d_in[14];
    const float* W3  = (const float*)d_in[15];
    const float* b3  = (const float*)d_in[16];

    const int N  = in_sizes[0] / F_IN;         // 50000
    const int E  = in_sizes[2];                // 800000
    const int MP = (N + 127) & ~127;           // 50048
    const int* row = ei;
    const int* col = ei + E;

    char* wsb = (char*)d_ws;
    unsigned long long* packed = (unsigned long long*)wsb; wsb = align16(wsb + (size_t)N * 8);
    float* dinv     = (float*)wsb;          wsb = align16(wsb + (size_t)N * 4);
    int*   csr_ptr  = (int*)wsb;            wsb = align16(wsb + (size_t)(N + 1) * 4);
    int*   cursor   = (int*)wsb;            wsb = align16(wsb + (size_t)N * 4);
    int*   blocksum = (int*)wsb;            wsb = align16(wsb + (size_t)SCAN_B * 4);
    int2*  csr_edge = (int2*)wsb;           wsb = align16(wsb + (size_t)E * 8);
    unsigned short* W1t = (unsigned short*)wsb;  wsb = align16(wsb + (size_t)F_IN * HF * 2);
    unsigned short* W2t = (unsigned short*)wsb;  wsb = align16(wsb + (size_t)HF * HF * 2);
    unsigned short* xbf  = (unsigned short*)wsb; wsb = align16(wsb + (size_t)MP * F_IN * 2);
    unsigned short* bufh = (unsigned short*)wsb; wsb = align16(wsb + (size_t)MP * HF * 2);
    unsigned short* bufa = (unsigned short*)wsb; wsb = align16(wsb + (size_t)MP * HF * 2);
    float* h3 = (float*)wsb;                wsb = align16(wsb + (size_t)N * OUT_F * 4);
    float* outf = (float*)d_out;

    const int TB = 256;
    const int nscan = (N + SCAN_B - 1) / SCAN_B;        // 196
    const int padx = (MP - N) * F_IN;
    const int pada = (MP - N) * HF;
    const int ncc = (E + TB - 1) / TB;                  // 3125 blocks: 1 edge/thread
    const int nchunk = (N * F_IN) / 8;
    const int nfill = (E + TB - 1) / TB;                // 3125
    const int ngemm = (MP / 128) * 2;                   // 782

    // --- packed deg/count: zero-init via DMA; self-loop folded into scan3 ---
    hipMemsetAsync(packed, 0, (size_t)N * 8, stream);

    // --- count atomics + x->bf16 + W transposes + pad zero (one dispatch) ---
    count_conv_kernel<<<ncc, TB, 0, stream>>>(
        col, ew, packed, x, xbf, W1, W1t, W2, W2t,
        xbf + (size_t)N * F_IN, bufa + (size_t)N * HF, E, nchunk, padx, pada);

    // --- CSR ptr build ---
    scan1_kernel<<<nscan, SCAN_B, 0, stream>>>(packed, csr_ptr, blocksum, N);
    scan3_dinv_kernel<<<nscan, SCAN_B, 0, stream>>>(csr_ptr, cursor, blocksum, packed, dinv, N, E, nscan);

    // --- fused: CSR fill (latency-bound, first) + layer-1 GEMM (compute) ---
    fill_gemm1_kernel<<<nfill + ngemm, TB, 0, stream>>>(
        row, col, ew, dinv, cursor, csr_edge, E, xbf, W1t, bufh, nfill);

    // --- layer 1 aggregation (+BN+ReLU) ---
    agg_kernel<0><<<((size_t)N * 64 + TB - 1) / TB, TB, 0, stream>>>(
        bufh, csr_ptr, csr_edge, dinv, b1, g1, be1, m1, v1, bufa, nullptr, nullptr, N);

    // --- layer 2 GEMM ---
    dim3 ggrid(MP / 128, HF / 128);   // (391, 2)
    gemm_kernel<<<ggrid, TB, 0, stream>>>(bufa, W2t, bufh, HF);

    // --- layer 2 aggregation (+BN+ReLU) fused with layer-3 GEMV ---
    agg_kernel<1><<<((size_t)N * 64 + TB - 1) / TB, TB, 0, stream>>>(
        bufh, csr_ptr, csr_edge, dinv, b2, g2, be2, m2, v2, nullptr, W3, h3, N);

    // --- final 2-feature aggregation ---
    out_kernel<<<(N + TB - 1) / TB, TB, 0, stream>>>(h3, csr_ptr, csr_edge, dinv, b3, outf, N);
}

// Round 14
// 528.932 us; speedup vs baseline: 1.0082x; 1.0082x over previous
//
#include <hip/hip_runtime.h>
#include <stdint.h>

#define F_IN 512
#define HF 256
#define OUT_F 2
#define BN_EPS 1e-5f
#define SCAN_B 256
#define LDSTR 36    // LDS row stride (shorts): 0 bank conflicts (measured R7)

typedef __attribute__((ext_vector_type(8))) short bf16x8;
typedef __attribute__((ext_vector_type(4))) float f32x4;

__device__ inline float bf2f(unsigned short u) {
    union { float f; uint32_t i; } v; v.i = ((uint32_t)u) << 16; return v.f;
}
__device__ inline unsigned short f2bf(float f) {
    union { float f; uint32_t i; } v; v.f = f;
    uint32_t r = v.i + 0x7FFFu + ((v.i >> 16) & 1u);   // RNE (finite values only)
    return (unsigned short)(r >> 16);
}

// ---------- count atomics + x->bf16 + W transposes + pad zero (all independent) ----------
__global__ void count_conv_kernel(const int* __restrict__ col,
                                  const float* __restrict__ w,
                                  unsigned long long* __restrict__ packed,   // pre-zeroed
                                  const float* __restrict__ x,
                                  unsigned short* __restrict__ xbf,
                                  const float* __restrict__ W1, unsigned short* __restrict__ W1t,
                                  const float* __restrict__ W2, unsigned short* __restrict__ W2t,
                                  unsigned short* __restrict__ xbf_pad,
                                  unsigned short* __restrict__ bufa_pad,
                                  int e, int nchunk, int padx, int pada) {
    int tid = blockIdx.x * blockDim.x + threadIdx.x;
    const int stride = gridDim.x * blockDim.x;
    if (tid < e) {
        unsigned long long add = (1ULL << 40)
            | (unsigned long long)__float2uint_rn(w[tid] * 1048576.0f);
        atomicAdd(&packed[col[tid]], add);
    }
    // x: fp32 -> bf16, 8 elems per chunk (streams under atomic latency)
    const float4* x4 = (const float4*)x;
    for (int c = tid; c < nchunk; c += stride) {
        float4 f0 = x4[2 * c];
        float4 f1 = x4[2 * c + 1];
        bf16x8 v;
        v[0] = (short)f2bf(f0.x); v[1] = (short)f2bf(f0.y);
        v[2] = (short)f2bf(f0.z); v[3] = (short)f2bf(f0.w);
        v[4] = (short)f2bf(f1.x); v[5] = (short)f2bf(f1.y);
        v[6] = (short)f2bf(f1.z); v[7] = (short)f2bf(f1.w);
        *(bf16x8*)(xbf + (size_t)c * 8) = v;
    }
    // weight transposes (bf16, [n][k] layout)
    for (int j = tid; j < F_IN * HF; j += stride) {
        int nn = j >> 9, k = j & (F_IN - 1);
        W1t[j] = f2bf(W1[(size_t)k * HF + nn]);
    }
    for (int j = tid; j < HF * HF; j += stride) {
        int nn = j >> 8, k = j & (HF - 1);
        W2t[j] = f2bf(W2[(size_t)k * HF + nn]);
    }
    for (int j = tid; j < padx; j += stride) xbf_pad[j] = 0;
    for (int j = tid; j < pada; j += stride) bufa_pad[j] = 0;
}

// ---------- single-kernel scan: local scan -> publish partial -> device barrier
// -> per-block re-reduce of partials -> csr_ptr/cursor/dinv. 196 blocks, all
// co-resident (tiny LDS/VGPR), so the counter spin cannot deadlock.
__global__ void scan_kernel(const unsigned long long* __restrict__ packed,
                            int* __restrict__ csr_ptr, int* __restrict__ cursor,
                            float* __restrict__ dinv,
                            int* __restrict__ partial, int* __restrict__ counter,
                            int n, int e, int nb) {
    __shared__ int tmp[SCAN_B];
    const int tid = threadIdx.x;
    const int bid = blockIdx.x;
    int i = bid * SCAN_B + tid;
    int v = (i < n) ? (int)(packed[i] >> 40) : 0;
    tmp[tid] = v;
    __syncthreads();
    for (int off = 1; off < SCAN_B; off <<= 1) {
        int t = 0;
        if (tid >= off) t = tmp[tid - off];
        __syncthreads();
        if (tid >= off) tmp[tid] += t;
        __syncthreads();
    }
    int excl = tmp[tid] - v;               // block-local exclusive
    if (tid == SCAN_B - 1) {
        partial[bid] = tmp[SCAN_B - 1];    // block total
        __threadfence();
        atomicAdd(counter, 1);
    }
    if (tid == 0) {                        // device-scope barrier on partials
        while (__hip_atomic_load(counter, __ATOMIC_ACQUIRE, __HIP_MEMORY_SCOPE_AGENT) < nb) {}
    }
    __syncthreads();
    tmp[tid] = (tid < nb && tid < bid) ? partial[tid] : 0;
    __syncthreads();
    for (int off = SCAN_B / 2; off > 0; off >>= 1) {
        if (tid < off) tmp[tid] += tmp[tid + off];
        __syncthreads();
    }
    int prefix = tmp[0];
    if (i < n) {
        int val = excl + prefix;
        csr_ptr[i] = val;
        cursor[i] = val;
        float deg = 1.0f + (float)(packed[i] & 0xFFFFFFFFFFULL) * (1.0f / 1048576.0f);
        dinv[i] = rsqrtf(deg);             // deg >= 1 (self-loop folded here)
    }
    if (i == 0) csr_ptr[n] = e;
}

// ---------- pipelined bf16 GEMM body (R10-verified structure) ----------
__device__ __forceinline__
void gemm_body(const unsigned short* __restrict__ A,
               const unsigned short* __restrict__ Bt,
               unsigned short* __restrict__ C, int K, int mblk, int nblk,
               unsigned short (*As)[128 * LDSTR], unsigned short (*Bs)[128 * LDSTR]) {
    const int tid  = threadIdx.x;
    const int lane = tid & 63;
    const int wv   = tid >> 6;
    const int wrow = wv >> 1, wcol = wv & 1;
    const int m0 = mblk * 128;
    const int n0 = nblk * 128;

    const int sr = tid >> 2;
    const int sc = (tid & 3) * 8;

    const unsigned short* pa0 = A + (size_t)(m0 + sr) * K + sc;
    const unsigned short* pa1 = A + (size_t)(m0 + sr + 64) * K + sc;
    const unsigned short* pb0 = Bt + (size_t)(n0 + sr) * K + sc;
    const unsigned short* pb1 = Bt + (size_t)(n0 + sr + 64) * K + sc;

    f32x4 zero4 = {0.0f, 0.0f, 0.0f, 0.0f};
    f32x4 acc[4][4];
    #pragma unroll
    for (int i = 0; i < 4; ++i)
        #pragma unroll
        for (int j = 0; j < 4; ++j) acc[i][j] = zero4;

    const int q8 = (lane >> 4) * 8;
    const int ml = lane & 15;

    bf16x8 va0 = *(const bf16x8*)pa0;
    bf16x8 va1 = *(const bf16x8*)pa1;
    bf16x8 vb0 = *(const bf16x8*)pb0;
    bf16x8 vb1 = *(const bf16x8*)pb1;

    const int nsteps = K >> 5;
    for (int s = 0; s < nsteps; ++s) {
        const int buf = s & 1;
        *(bf16x8*)&As[buf][sr * LDSTR + sc]        = va0;
        *(bf16x8*)&As[buf][(sr + 64) * LDSTR + sc] = va1;
        *(bf16x8*)&Bs[buf][sr * LDSTR + sc]        = vb0;
        *(bf16x8*)&Bs[buf][(sr + 64) * LDSTR + sc] = vb1;
        __syncthreads();
        if (s + 1 < nsteps) {
            int off = (s + 1) * 32;
            va0 = *(const bf16x8*)(pa0 + off);
            va1 = *(const bf16x8*)(pa1 + off);
            vb0 = *(const bf16x8*)(pb0 + off);
            vb1 = *(const bf16x8*)(pb1 + off);
        }
        bf16x8 af[4], bfr[4];
        #pragma unroll
        for (int i = 0; i < 4; ++i)
            af[i] = *(const bf16x8*)&As[buf][(wrow * 64 + i * 16 + ml) * LDSTR + q8];
        #pragma unroll
        for (int j = 0; j < 4; ++j)
            bfr[j] = *(const bf16x8*)&Bs[buf][(wcol * 64 + j * 16 + ml) * LDSTR + q8];
        #pragma unroll
        for (int i = 0; i < 4; ++i)
            #pragma unroll
            for (int j = 0; j < 4; ++j)
                acc[i][j] = __builtin_amdgcn_mfma_f32_16x16x32_bf16(af[i], bfr[j], acc[i][j], 0, 0, 0);
    }

    const int q4 = (lane >> 4) * 4;
    #pragma unroll
    for (int i = 0; i < 4; ++i) {
        #pragma unroll
        for (int j = 0; j < 4; ++j) {
            #pragma unroll
            for (int rg = 0; rg < 4; ++rg) {
                int r = m0 + wrow * 64 + i * 16 + q4 + rg;
                int c = n0 + wcol * 64 + j * 16 + ml;
                C[(size_t)r * HF + c] = f2bf(acc[i][j][rg]);
            }
        }
    }
}

// ---------- fused: CSR fill (nfill grid-stride blocks, co-resident) + GEMM1 ----------
// nfill=512 so fill + first 512 GEMM blocks are ALL resident at t=0 (4 blocks/CU
// LDS cap) -> fill's atomic latency hides UNDER gemm compute (R13 lesson: 3125
// fill blocks serialized BEFORE gemm; sized-down grid-stride avoids that).
__global__ __launch_bounds__(256)
void fill_gemm1_kernel(const int* __restrict__ row, const int* __restrict__ col,
                       const float* __restrict__ w, const float* __restrict__ dinv,
                       int* __restrict__ cursor, int2* __restrict__ csr_edge, int e,
                       const unsigned short* __restrict__ A,
                       const unsigned short* __restrict__ Bt,
                       unsigned short* __restrict__ C, int nfill) {
    __shared__ unsigned short As[2][128 * LDSTR];
    __shared__ unsigned short Bs[2][128 * LDSTR];
    int bid = blockIdx.x;
    if (bid < nfill) {
        const int stride = nfill * 256;
        for (int i = bid * 256 + (int)threadIdx.x; i < e; i += stride) {
            int r = row[i], c = col[i];
            int pos = atomicAdd(&cursor[c], 1);
            float nrm = dinv[r] * w[i] * dinv[c];
            csr_edge[pos] = make_int2(r, __float_as_int(nrm));
        }
    } else {
        int gb = bid - nfill;
        gemm_body(A, Bt, C, F_IN, gb >> 1, gb & 1, As, Bs);
    }
}

// ---------- standalone GEMM (layer 2) ----------
__global__ __launch_bounds__(256)
void gemm_kernel(const unsigned short* __restrict__ A,
                 const unsigned short* __restrict__ Bt,
                 unsigned short* __restrict__ C, int K) {
    __shared__ unsigned short As[2][128 * LDSTR];
    __shared__ unsigned short Bs[2][128 * LDSTR];
    gemm_body(A, Bt, C, K, blockIdx.x, blockIdx.y, As, Bs);
}

// ---------- fused CSR gather + self-loop + bias + BN + ReLU (R12 pipeline) ----------
template<int FINAL>
__global__ void agg_kernel(const unsigned short* __restrict__ h,
                           const int* __restrict__ ptr,
                           const int2* __restrict__ edge,
                           const float* __restrict__ dinv,
                           const float* __restrict__ b, const float* __restrict__ g,
                           const float* __restrict__ be, const float* __restrict__ m,
                           const float* __restrict__ v,
                           unsigned short* __restrict__ out,
                           const float* __restrict__ W3, float* __restrict__ h3, int n) {
    int wid  = (blockIdx.x * blockDim.x + threadIdx.x) >> 6;
    int lane = threadIdx.x & 63;
    if (wid >= n) return;
    int p0 = ptr[wid], p1 = ptr[wid + 1];
    const int fo = lane * 4;
    float a0 = 0.f, a1 = 0.f, a2 = 0.f, a3 = 0.f;

    const int cnt = p1 - p0;
    const int nb  = cnt >> 3;       // full batches of 8

    int2 edC[8], edN[8];
    ushort4 hvC[8];

    if (nb > 0) {
        #pragma unroll
        for (int k = 0; k < 8; ++k) edC[k] = edge[p0 + k];
        if (nb > 1) {
            #pragma unroll
            for (int k = 0; k < 8; ++k) edN[k] = edge[p0 + 8 + k];
        }
        #pragma unroll
        for (int k = 0; k < 8; ++k)
            hvC[k] = *(const ushort4*)(h + (size_t)edC[k].x * HF + fo);

        for (int bb = 0; bb < nb; ++bb) {
            ushort4 hvN[8];
            int2 edN2[8];
            if (bb + 1 < nb) {
                if (bb + 2 < nb) {
                    int pp = p0 + (bb + 2) * 8;
                    #pragma unroll
                    for (int k = 0; k < 8; ++k) edN2[k] = edge[pp + k];
                }
                #pragma unroll
                for (int k = 0; k < 8; ++k)
                    hvN[k] = *(const ushort4*)(h + (size_t)edN[k].x * HF + fo);
            }
            #pragma unroll
            for (int k = 0; k < 8; ++k) {
                float nw = __int_as_float(edC[k].y);
                a0 += nw * bf2f(hvC[k].x);
                a1 += nw * bf2f(hvC[k].y);
                a2 += nw * bf2f(hvC[k].z);
                a3 += nw * bf2f(hvC[k].w);
            }
            #pragma unroll
            for (int k = 0; k < 8; ++k) { edC[k] = edN[k]; edN[k] = edN2[k]; hvC[k] = hvN[k]; }
        }
    }
    const int pend = p0 + nb * 8;
    if (pend < p1) {
        int2 ed[8];
        float wv[8];
        #pragma unroll
        for (int k = 0; k < 8; ++k) {
            int idx = pend + k < p1 ? pend + k : p1 - 1;
            ed[k] = edge[idx];
            wv[k] = (pend + k < p1) ? __int_as_float(ed[k].y) : 0.0f;
        }
        ushort4 hv[8];
        #pragma unroll
        for (int k = 0; k < 8; ++k)
            hv[k] = *(const ushort4*)(h + (size_t)ed[k].x * HF + fo);
        #pragma unroll
        for (int k = 0; k < 8; ++k) {
            a0 += wv[k] * bf2f(hv[k].x);
            a1 += wv[k] * bf2f(hv[k].y);
            a2 += wv[k] * bf2f(hv[k].z);
            a3 += wv[k] * bf2f(hv[k].w);
        }
    }
    // self loop: weight 1, norm = dinv^2
    float s = dinv[wid];
    float sl = s * s;
    ushort4 hv = *(const ushort4*)(h + (size_t)wid * HF + fo);
    a0 += sl * bf2f(hv.x);
    a1 += sl * bf2f(hv.y);
    a2 += sl * bf2f(hv.z);
    a3 += sl * bf2f(hv.w);

    float4 bb  = *(const float4*)(b + fo);
    float4 gg  = *(const float4*)(g + fo);
    float4 bee = *(const float4*)(be + fo);
    float4 mm  = *(const float4*)(m + fo);
    float4 vv  = *(const float4*)(v + fo);
    float f0 = fmaxf((a0 + bb.x - mm.x) * rsqrtf(vv.x + BN_EPS) * gg.x + bee.x, 0.f);
    float f1 = fmaxf((a1 + bb.y - mm.y) * rsqrtf(vv.y + BN_EPS) * gg.y + bee.y, 0.f);
    float f2 = fmaxf((a2 + bb.z - mm.z) * rsqrtf(vv.z + BN_EPS) * gg.z + bee.z, 0.f);
    float f3 = fmaxf((a3 + bb.w - mm.w) * rsqrtf(vv.w + BN_EPS) * gg.w + bee.w, 0.f);

    if (!FINAL) {
        ushort4 o;
        o.x = f2bf(f0); o.y = f2bf(f1); o.z = f2bf(f2); o.w = f2bf(f3);
        *(ushort4*)(out + (size_t)wid * HF + fo) = o;
    } else {
        float4 w0 = *(const float4*)(W3 + fo * 2);
        float4 w1 = *(const float4*)(W3 + fo * 2 + 4);
        float s0 = f0 * w0.x + f1 * w0.z + f2 * w1.x + f3 * w1.z;
        float s1 = f0 * w0.y + f1 * w0.w + f2 * w1.y + f3 * w1.w;
        #pragma unroll
        for (int o = 32; o > 0; o >>= 1) {
            s0 += __shfl_down(s0, o, 64);
            s1 += __shfl_down(s1, o, 64);
        }
        if (lane == 0) {
            h3[wid * 2 + 0] = s0;
            h3[wid * 2 + 1] = s1;
        }
    }
}

// ---------- final: CSR gather (2 features) + self-loop + bias ----------
__global__ void out_kernel(const float* __restrict__ h3,
                           const int* __restrict__ ptr, const int2* __restrict__ edge,
                           const float* __restrict__ dinv,
                           const float* __restrict__ b3, float* __restrict__ out, int n) {
    int i = blockIdx.x * blockDim.x + threadIdx.x;
    if (i >= n) return;
    int p0 = ptr[i], p1 = ptr[i + 1];
    float a0 = 0.f, a1 = 0.f;
    for (int p = p0; p < p1; p += 4) {
        #pragma unroll
        for (int k = 0; k < 4; ++k) {
            int idx = p + k < p1 ? p + k : p1 - 1;
            int2 e = edge[idx];
            float nw = (p + k < p1) ? __int_as_float(e.y) : 0.0f;
            float2 u = *(const float2*)(h3 + 2 * e.x);
            a0 += nw * u.x;
            a1 += nw * u.y;
        }
    }
    float s = dinv[i];
    float sl = s * s;
    out[2 * i + 0] = a0 + sl * h3[2 * i + 0] + b3[0];
    out[2 * i + 1] = a1 + sl * h3[2 * i + 1] + b3[1];
}

static inline char* align16(char* p) {
    return (char*)(((uintptr_t)p + 15) & ~(uintptr_t)15);
}

extern "C" void kernel_launch(void* const* d_in, const int* in_sizes, int n_in,
                              void* d_out, int out_size, void* d_ws, size_t ws_size,
                              hipStream_t stream) {
    const float* x   = (const float*)d_in[0];
    const int*   ei  = (const int*)d_in[1];    // int64 in reference -> int32 in harness
    const float* ew  = (const float*)d_in[2];
    const float* W1  = (const float*)d_in[3];
    const float* b1  = (const float*)d_in[4];
    const float* g1  = (const float*)d_in[5];
    const float* be1 = (const float*)d_in[6];
    const float* m1  = (const float*)d_in[7];
    const float* v1  = (const float*)d_in[8];
    const float* W2  = (const float*)d_in[9];
    const float* b2  = (const float*)d_in[10];
    const float* g2  = (const float*)d_in[11];
    const float* be2 = (const float*)d_in[12];
    const float* m2  = (const float*)d_in[13];
    const float* v2  = (const float*)d_in[14];
    const float* W3  = (const float*)d_in[15];
    const float* b3  = (const float*)d_in[16];

    const int N  = in_sizes[0] / F_IN;         // 50000
    const int E  = in_sizes[2];                // 800000
    const int MP = (N + 127) & ~127;           // 50048
    const int* row = ei;
    const int* col = ei + E;

    char* wsb = (char*)d_ws;
    unsigned long long* packed = (unsigned long long*)wsb; wsb = align16(wsb + (size_t)(N + 2) * 8);
    int* counter    = (int*)(packed + N);      // zeroed together with packed
    float* dinv     = (float*)wsb;          wsb = align16(wsb + (size_t)N * 4);
    int*   csr_ptr  = (int*)wsb;            wsb = align16(wsb + (size_t)(N + 1) * 4);
    int*   cursor   = (int*)wsb;            wsb = align16(wsb + (size_t)N * 4);
    int*   partial  = (int*)wsb;            wsb = align16(wsb + (size_t)SCAN_B * 4);
    int2*  csr_edge = (int2*)wsb;           wsb = align16(wsb + (size_t)E * 8);
    unsigned short* W1t = (unsigned short*)wsb;  wsb = align16(wsb + (size_t)F_IN * HF * 2);
    unsigned short* W2t = (unsigned short*)wsb;  wsb = align16(wsb + (size_t)HF * HF * 2);
    unsigned short* xbf  = (unsigned short*)wsb; wsb = align16(wsb + (size_t)MP * F_IN * 2);
    unsigned short* bufh = (unsigned short*)wsb; wsb = align16(wsb + (size_t)MP * HF * 2);
    unsigned short* bufa = (unsigned short*)wsb; wsb = align16(wsb + (size_t)MP * HF * 2);
    float* h3 = (float*)wsb;                wsb = align16(wsb + (size_t)N * OUT_F * 4);
    float* outf = (float*)d_out;

    const int TB = 256;
    const int nscan = (N + SCAN_B - 1) / SCAN_B;        // 196
    const int padx = (MP - N) * F_IN;
    const int pada = (MP - N) * HF;
    const int ncc = (E + TB - 1) / TB;                  // 3125
    const int nchunk = (N * F_IN) / 8;
    const int nfill = 512;                              // co-residency sized (see kernel)
    const int ngemm = (MP / 128) * 2;                   // 782

    // --- packed deg/count + scan counter: zero via one DMA memset ---
    hipMemsetAsync(packed, 0, (size_t)(N + 2) * 8, stream);

    // --- count atomics + x->bf16 + W transposes + pad zero (one dispatch) ---
    count_conv_kernel<<<ncc, TB, 0, stream>>>(
        col, ew, packed, x, xbf, W1, W1t, W2, W2t,
        xbf + (size_t)N * F_IN, bufa + (size_t)N * HF, E, nchunk, padx, pada);

    // --- CSR ptr build: single kernel (internal device barrier) ---
    scan_kernel<<<nscan, SCAN_B, 0, stream>>>(packed, csr_ptr, cursor, dinv,
                                              partial, counter, N, E, nscan);

    // --- fused: CSR fill (512 co-resident grid-stride blocks) + layer-1 GEMM ---
    fill_gemm1_kernel<<<nfill + ngemm, TB, 0, stream>>>(
        row, col, ew, dinv, cursor, csr_edge, E, xbf, W1t, bufh, nfill);

    // --- layer 1 aggregation (+BN+ReLU) ---
    agg_kernel<0><<<((size_t)N * 64 + TB - 1) / TB, TB, 0, stream>>>(
        bufh, csr_ptr, csr_edge, dinv, b1, g1, be1, m1, v1, bufa, nullptr, nullptr, N);

    // --- layer 2 GEMM ---
    dim3 ggrid(MP / 128, HF / 128);   // (391, 2)
    gemm_kernel<<<ggrid, TB, 0, stream>>>(bufa, W2t, bufh, HF);

    // --- layer 2 aggregation (+BN+ReLU) fused with layer-3 GEMV ---
    agg_kernel<1><<<((size_t)N * 64 + TB - 1) / TB, TB, 0, stream>>>(
        bufh, csr_ptr, csr_edge, dinv, b2, g2, be2, m2, v2, nullptr, W3, h3, N);

    // --- final 2-feature aggregation ---
    out_kernel<<<(N + TB - 1) / TB, TB, 0, stream>>>(h3, csr_ptr, csr_edge, dinv, b3, outf, N);
}

// Round 15
// 475.310 us; speedup vs baseline: 1.1219x; 1.1128x over previous
//
#include <hip/hip_runtime.h>
#include <stdint.h>

#define F_IN 512
#define HF 256
#define OUT_F 2
#define BN_EPS 1e-5f
#define SCAN_B 256
#define LDSTR 36    // LDS row stride (shorts): 0 bank conflicts (measured R7)

typedef __attribute__((ext_vector_type(8))) short bf16x8;
typedef __attribute__((ext_vector_type(4))) float f32x4;

__device__ inline float bf2f(unsigned short u) {
    union { float f; uint32_t i; } v; v.i = ((uint32_t)u) << 16; return v.f;
}
__device__ inline unsigned short f2bf(float f) {
    union { float f; uint32_t i; } v; v.f = f;
    uint32_t r = v.i + 0x7FFFu + ((v.i >> 16) & 1u);   // RNE (finite values only)
    return (unsigned short)(r >> 16);
}

// ---------- count atomics + x->bf16 + W transposes + pad zero (all independent) ----------
__global__ void count_conv_kernel(const int* __restrict__ col,
                                  const float* __restrict__ w,
                                  unsigned long long* __restrict__ packed,   // pre-zeroed
                                  const float* __restrict__ x,
                                  unsigned short* __restrict__ xbf,
                                  const float* __restrict__ W1, unsigned short* __restrict__ W1t,
                                  const float* __restrict__ W2, unsigned short* __restrict__ W2t,
                                  unsigned short* __restrict__ xbf_pad,
                                  unsigned short* __restrict__ bufa_pad,
                                  int e, int nchunk, int padx, int pada) {
    int tid = blockIdx.x * blockDim.x + threadIdx.x;
    const int stride = gridDim.x * blockDim.x;
    if (tid < e) {
        unsigned long long add = (1ULL << 40)
            | (unsigned long long)__float2uint_rn(w[tid] * 1048576.0f);
        atomicAdd(&packed[col[tid]], add);
    }
    // x: fp32 -> bf16, 8 elems per chunk (streams under atomic latency)
    const float4* x4 = (const float4*)x;
    for (int c = tid; c < nchunk; c += stride) {
        float4 f0 = x4[2 * c];
        float4 f1 = x4[2 * c + 1];
        bf16x8 v;
        v[0] = (short)f2bf(f0.x); v[1] = (short)f2bf(f0.y);
        v[2] = (short)f2bf(f0.z); v[3] = (short)f2bf(f0.w);
        v[4] = (short)f2bf(f1.x); v[5] = (short)f2bf(f1.y);
        v[6] = (short)f2bf(f1.z); v[7] = (short)f2bf(f1.w);
        *(bf16x8*)(xbf + (size_t)c * 8) = v;
    }
    // weight transposes (bf16, [n][k] layout)
    for (int j = tid; j < F_IN * HF; j += stride) {
        int nn = j >> 9, k = j & (F_IN - 1);
        W1t[j] = f2bf(W1[(size_t)k * HF + nn]);
    }
    for (int j = tid; j < HF * HF; j += stride) {
        int nn = j >> 8, k = j & (HF - 1);
        W2t[j] = f2bf(W2[(size_t)k * HF + nn]);
    }
    for (int j = tid; j < padx; j += stride) xbf_pad[j] = 0;
    for (int j = tid; j < pada; j += stride) bufa_pad[j] = 0;
}

// ---------- single-kernel scan: local scan -> publish partial -> device barrier
// -> per-block re-reduce of partials -> csr_ptr/cursor/dinv. 196 blocks, all
// co-resident (tiny LDS/VGPR), so the counter spin cannot deadlock. (R14-verified)
__global__ void scan_kernel(const unsigned long long* __restrict__ packed,
                            int* __restrict__ csr_ptr, int* __restrict__ cursor,
                            float* __restrict__ dinv,
                            int* __restrict__ partial, int* __restrict__ counter,
                            int n, int e, int nb) {
    __shared__ int tmp[SCAN_B];
    const int tid = threadIdx.x;
    const int bid = blockIdx.x;
    int i = bid * SCAN_B + tid;
    int v = (i < n) ? (int)(packed[i] >> 40) : 0;
    tmp[tid] = v;
    __syncthreads();
    for (int off = 1; off < SCAN_B; off <<= 1) {
        int t = 0;
        if (tid >= off) t = tmp[tid - off];
        __syncthreads();
        if (tid >= off) tmp[tid] += t;
        __syncthreads();
    }
    int excl = tmp[tid] - v;               // block-local exclusive
    if (tid == SCAN_B - 1) {
        partial[bid] = tmp[SCAN_B - 1];    // block total
        __threadfence();
        atomicAdd(counter, 1);
    }
    if (tid == 0) {                        // device-scope barrier on partials
        while (__hip_atomic_load(counter, __ATOMIC_ACQUIRE, __HIP_MEMORY_SCOPE_AGENT) < nb) {}
    }
    __syncthreads();
    tmp[tid] = (tid < nb && tid < bid) ? partial[tid] : 0;
    __syncthreads();
    for (int off = SCAN_B / 2; off > 0; off >>= 1) {
        if (tid < off) tmp[tid] += tmp[tid + off];
        __syncthreads();
    }
    int prefix = tmp[0];
    if (i < n) {
        int val = excl + prefix;
        csr_ptr[i] = val;
        cursor[i] = val;
        float deg = 1.0f + (float)(packed[i] & 0xFFFFFFFFFFULL) * (1.0f / 1048576.0f);
        dinv[i] = rsqrtf(deg);             // deg >= 1 (self-loop folded here)
    }
    if (i == 0) csr_ptr[n] = e;
}

// ---------- CSR fill: standalone (small LDS -> high occupancy; R12-proven) ----------
__global__ void fill_kernel(const int* __restrict__ row, const int* __restrict__ col,
                            const float* __restrict__ w, const float* __restrict__ dinv,
                            int* __restrict__ cursor, int2* __restrict__ csr_edge, int e) {
    int i = blockIdx.x * blockDim.x + threadIdx.x;
    if (i < e) {
        int r = row[i], c = col[i];
        int pos = atomicAdd(&cursor[c], 1);
        float nrm = dinv[r] * w[i] * dinv[c];
        csr_edge[pos] = make_int2(r, __float_as_int(nrm));
    }
}

// ---------- pipelined bf16 GEMM: C[MP,256] = A[MP,K] @ Bt[256,K]^T ----------
// BM=BN=128, BK=32; reg prefetch + LDS dbuf, ONE barrier per K-step (R10-verified).
__global__ __launch_bounds__(256)
void gemm_kernel(const unsigned short* __restrict__ A,
                 const unsigned short* __restrict__ Bt,
                 unsigned short* __restrict__ C, int K) {
    __shared__ unsigned short As[2][128 * LDSTR];
    __shared__ unsigned short Bs[2][128 * LDSTR];
    const int tid  = threadIdx.x;
    const int lane = tid & 63;
    const int wv   = tid >> 6;
    const int wrow = wv >> 1, wcol = wv & 1;
    const int m0 = blockIdx.x * 128;
    const int n0 = blockIdx.y * 128;

    const int sr = tid >> 2;
    const int sc = (tid & 3) * 8;

    const unsigned short* pa0 = A + (size_t)(m0 + sr) * K + sc;
    const unsigned short* pa1 = A + (size_t)(m0 + sr + 64) * K + sc;
    const unsigned short* pb0 = Bt + (size_t)(n0 + sr) * K + sc;
    const unsigned short* pb1 = Bt + (size_t)(n0 + sr + 64) * K + sc;

    f32x4 zero4 = {0.0f, 0.0f, 0.0f, 0.0f};
    f32x4 acc[4][4];
    #pragma unroll
    for (int i = 0; i < 4; ++i)
        #pragma unroll
        for (int j = 0; j < 4; ++j) acc[i][j] = zero4;

    const int q8 = (lane >> 4) * 8;
    const int ml = lane & 15;

    bf16x8 va0 = *(const bf16x8*)pa0;
    bf16x8 va1 = *(const bf16x8*)pa1;
    bf16x8 vb0 = *(const bf16x8*)pb0;
    bf16x8 vb1 = *(const bf16x8*)pb1;

    const int nsteps = K >> 5;
    for (int s = 0; s < nsteps; ++s) {
        const int buf = s & 1;
        *(bf16x8*)&As[buf][sr * LDSTR + sc]        = va0;
        *(bf16x8*)&As[buf][(sr + 64) * LDSTR + sc] = va1;
        *(bf16x8*)&Bs[buf][sr * LDSTR + sc]        = vb0;
        *(bf16x8*)&Bs[buf][(sr + 64) * LDSTR + sc] = vb1;
        __syncthreads();
        if (s + 1 < nsteps) {
            int off = (s + 1) * 32;
            va0 = *(const bf16x8*)(pa0 + off);
            va1 = *(const bf16x8*)(pa1 + off);
            vb0 = *(const bf16x8*)(pb0 + off);
            vb1 = *(const bf16x8*)(pb1 + off);
        }
        bf16x8 af[4], bfr[4];
        #pragma unroll
        for (int i = 0; i < 4; ++i)
            af[i] = *(const bf16x8*)&As[buf][(wrow * 64 + i * 16 + ml) * LDSTR + q8];
        #pragma unroll
        for (int j = 0; j < 4; ++j)
            bfr[j] = *(const bf16x8*)&Bs[buf][(wcol * 64 + j * 16 + ml) * LDSTR + q8];
        #pragma unroll
        for (int i = 0; i < 4; ++i)
            #pragma unroll
            for (int j = 0; j < 4; ++j)
                acc[i][j] = __builtin_amdgcn_mfma_f32_16x16x32_bf16(af[i], bfr[j], acc[i][j], 0, 0, 0);
    }

    const int q4 = (lane >> 4) * 4;
    #pragma unroll
    for (int i = 0; i < 4; ++i) {
        #pragma unroll
        for (int j = 0; j < 4; ++j) {
            #pragma unroll
            for (int rg = 0; rg < 4; ++rg) {
                int r = m0 + wrow * 64 + i * 16 + q4 + rg;
                int c = n0 + wcol * 64 + j * 16 + ml;
                C[(size_t)r * HF + c] = f2bf(acc[i][j][rg]);
            }
        }
    }
}

// ---------- fused CSR gather + self-loop + bias + BN + ReLU (R12 pipeline) ----------
template<int FINAL>
__global__ void agg_kernel(const unsigned short* __restrict__ h,
                           const int* __restrict__ ptr,
                           const int2* __restrict__ edge,
                           const float* __restrict__ dinv,
                           const float* __restrict__ b, const float* __restrict__ g,
                           const float* __restrict__ be, const float* __restrict__ m,
                           const float* __restrict__ v,
                           unsigned short* __restrict__ out,
                           const float* __restrict__ W3, float* __restrict__ h3, int n) {
    int wid  = (blockIdx.x * blockDim.x + threadIdx.x) >> 6;
    int lane = threadIdx.x & 63;
    if (wid >= n) return;
    int p0 = ptr[wid], p1 = ptr[wid + 1];
    const int fo = lane * 4;
    float a0 = 0.f, a1 = 0.f, a2 = 0.f, a3 = 0.f;

    const int cnt = p1 - p0;
    const int nb  = cnt >> 3;       // full batches of 8

    int2 edC[8], edN[8];
    ushort4 hvC[8];

    if (nb > 0) {
        #pragma unroll
        for (int k = 0; k < 8; ++k) edC[k] = edge[p0 + k];
        if (nb > 1) {
            #pragma unroll
            for (int k = 0; k < 8; ++k) edN[k] = edge[p0 + 8 + k];
        }
        #pragma unroll
        for (int k = 0; k < 8; ++k)
            hvC[k] = *(const ushort4*)(h + (size_t)edC[k].x * HF + fo);

        for (int bb = 0; bb < nb; ++bb) {
            ushort4 hvN[8];
            int2 edN2[8];
            if (bb + 1 < nb) {
                if (bb + 2 < nb) {
                    int pp = p0 + (bb + 2) * 8;
                    #pragma unroll
                    for (int k = 0; k < 8; ++k) edN2[k] = edge[pp + k];
                }
                #pragma unroll
                for (int k = 0; k < 8; ++k)
                    hvN[k] = *(const ushort4*)(h + (size_t)edN[k].x * HF + fo);
            }
            #pragma unroll
            for (int k = 0; k < 8; ++k) {
                float nw = __int_as_float(edC[k].y);
                a0 += nw * bf2f(hvC[k].x);
                a1 += nw * bf2f(hvC[k].y);
                a2 += nw * bf2f(hvC[k].z);
                a3 += nw * bf2f(hvC[k].w);
            }
            #pragma unroll
            for (int k = 0; k < 8; ++k) { edC[k] = edN[k]; edN[k] = edN2[k]; hvC[k] = hvN[k]; }
        }
    }
    const int pend = p0 + nb * 8;
    if (pend < p1) {
        int2 ed[8];
        float wv[8];
        #pragma unroll
        for (int k = 0; k < 8; ++k) {
            int idx = pend + k < p1 ? pend + k : p1 - 1;
            ed[k] = edge[idx];
            wv[k] = (pend + k < p1) ? __int_as_float(ed[k].y) : 0.0f;
        }
        ushort4 hv[8];
        #pragma unroll
        for (int k = 0; k < 8; ++k)
            hv[k] = *(const ushort4*)(h + (size_t)ed[k].x * HF + fo);
        #pragma unroll
        for (int k = 0; k < 8; ++k) {
            a0 += wv[k] * bf2f(hv[k].x);
            a1 += wv[k] * bf2f(hv[k].y);
            a2 += wv[k] * bf2f(hv[k].z);
            a3 += wv[k] * bf2f(hv[k].w);
        }
    }
    // self loop: weight 1, norm = dinv^2
    float s = dinv[wid];
    float sl = s * s;
    ushort4 hv = *(const ushort4*)(h + (size_t)wid * HF + fo);
    a0 += sl * bf2f(hv.x);
    a1 += sl * bf2f(hv.y);
    a2 += sl * bf2f(hv.z);
    a3 += sl * bf2f(hv.w);

    float4 bb  = *(const float4*)(b + fo);
    float4 gg  = *(const float4*)(g + fo);
    float4 bee = *(const float4*)(be + fo);
    float4 mm  = *(const float4*)(m + fo);
    float4 vv  = *(const float4*)(v + fo);
    float f0 = fmaxf((a0 + bb.x - mm.x) * rsqrtf(vv.x + BN_EPS) * gg.x + bee.x, 0.f);
    float f1 = fmaxf((a1 + bb.y - mm.y) * rsqrtf(vv.y + BN_EPS) * gg.y + bee.y, 0.f);
    float f2 = fmaxf((a2 + bb.z - mm.z) * rsqrtf(vv.z + BN_EPS) * gg.z + bee.z, 0.f);
    float f3 = fmaxf((a3 + bb.w - mm.w) * rsqrtf(vv.w + BN_EPS) * gg.w + bee.w, 0.f);

    if (!FINAL) {
        ushort4 o;
        o.x = f2bf(f0); o.y = f2bf(f1); o.z = f2bf(f2); o.w = f2bf(f3);
        *(ushort4*)(out + (size_t)wid * HF + fo) = o;
    } else {
        float4 w0 = *(const float4*)(W3 + fo * 2);
        float4 w1 = *(const float4*)(W3 + fo * 2 + 4);
        float s0 = f0 * w0.x + f1 * w0.z + f2 * w1.x + f3 * w1.z;
        float s1 = f0 * w0.y + f1 * w0.w + f2 * w1.y + f3 * w1.w;
        #pragma unroll
        for (int o = 32; o > 0; o >>= 1) {
            s0 += __shfl_down(s0, o, 64);
            s1 += __shfl_down(s1, o, 64);
        }
        if (lane == 0) {
            h3[wid * 2 + 0] = s0;
            h3[wid * 2 + 1] = s1;
        }
    }
}

// ---------- final: CSR gather (2 features) + self-loop + bias ----------
__global__ void out_kernel(const float* __restrict__ h3,
                           const int* __restrict__ ptr, const int2* __restrict__ edge,
                           const float* __restrict__ dinv,
                           const float* __restrict__ b3, float* __restrict__ out, int n) {
    int i = blockIdx.x * blockDim.x + threadIdx.x;
    if (i >= n) return;
    int p0 = ptr[i], p1 = ptr[i + 1];
    float a0 = 0.f, a1 = 0.f;
    for (int p = p0; p < p1; p += 4) {
        #pragma unroll
        for (int k = 0; k < 4; ++k) {
            int idx = p + k < p1 ? p + k : p1 - 1;
            int2 e = edge[idx];
            float nw = (p + k < p1) ? __int_as_float(e.y) : 0.0f;
            float2 u = *(const float2*)(h3 + 2 * e.x);
            a0 += nw * u.x;
            a1 += nw * u.y;
        }
    }
    float s = dinv[i];
    float sl = s * s;
    out[2 * i + 0] = a0 + sl * h3[2 * i + 0] + b3[0];
    out[2 * i + 1] = a1 + sl * h3[2 * i + 1] + b3[1];
}

static inline char* align16(char* p) {
    return (char*)(((uintptr_t)p + 15) & ~(uintptr_t)15);
}

extern "C" void kernel_launch(void* const* d_in, const int* in_sizes, int n_in,
                              void* d_out, int out_size, void* d_ws, size_t ws_size,
                              hipStream_t stream) {
    const float* x   = (const float*)d_in[0];
    const int*   ei  = (const int*)d_in[1];    // int64 in reference -> int32 in harness
    const float* ew  = (const float*)d_in[2];
    const float* W1  = (const float*)d_in[3];
    const float* b1  = (const float*)d_in[4];
    const float* g1  = (const float*)d_in[5];
    const float* be1 = (const float*)d_in[6];
    const float* m1  = (const float*)d_in[7];
    const float* v1  = (const float*)d_in[8];
    const float* W2  = (const float*)d_in[9];
    const float* b2  = (const float*)d_in[10];
    const float* g2  = (const float*)d_in[11];
    const float* be2 = (const float*)d_in[12];
    const float* m2  = (const float*)d_in[13];
    const float* v2  = (const float*)d_in[14];
    const float* W3  = (const float*)d_in[15];
    const float* b3  = (const float*)d_in[16];

    const int N  = in_sizes[0] / F_IN;         // 50000
    const int E  = in_sizes[2];                // 800000
    const int MP = (N + 127) & ~127;           // 50048
    const int* row = ei;
    const int* col = ei + E;

    char* wsb = (char*)d_ws;
    unsigned long long* packed = (unsigned long long*)wsb; wsb = align16(wsb + (size_t)(N + 2) * 8);
    int* counter    = (int*)(packed + N);      // zeroed together with packed
    float* dinv     = (float*)wsb;          wsb = align16(wsb + (size_t)N * 4);
    int*   csr_ptr  = (int*)wsb;            wsb = align16(wsb + (size_t)(N + 1) * 4);
    int*   cursor   = (int*)wsb;            wsb = align16(wsb + (size_t)N * 4);
    int*   partial  = (int*)wsb;            wsb = align16(wsb + (size_t)SCAN_B * 4);
    int2*  csr_edge = (int2*)wsb;           wsb = align16(wsb + (size_t)E * 8);
    unsigned short* W1t = (unsigned short*)wsb;  wsb = align16(wsb + (size_t)F_IN * HF * 2);
    unsigned short* W2t = (unsigned short*)wsb;  wsb = align16(wsb + (size_t)HF * HF * 2);
    unsigned short* xbf  = (unsigned short*)wsb; wsb = align16(wsb + (size_t)MP * F_IN * 2);
    unsigned short* bufh = (unsigned short*)wsb; wsb = align16(wsb + (size_t)MP * HF * 2);
    unsigned short* bufa = (unsigned short*)wsb; wsb = align16(wsb + (size_t)MP * HF * 2);
    float* h3 = (float*)wsb;                wsb = align16(wsb + (size_t)N * OUT_F * 4);
    float* outf = (float*)d_out;

    const int TB = 256;
    const int nscan = (N + SCAN_B - 1) / SCAN_B;        // 196
    const int padx = (MP - N) * F_IN;
    const int pada = (MP - N) * HF;
    const int ncc = (E + TB - 1) / TB;                  // 3125
    const int nchunk = (N * F_IN) / 8;

    // --- packed deg/count + scan counter: zero via one DMA memset ---
    hipMemsetAsync(packed, 0, (size_t)(N + 2) * 8, stream);

    // --- count atomics + x->bf16 + W transposes + pad zero (one dispatch) ---
    count_conv_kernel<<<ncc, TB, 0, stream>>>(
        col, ew, packed, x, xbf, W1, W1t, W2, W2t,
        xbf + (size_t)N * F_IN, bufa + (size_t)N * HF, E, nchunk, padx, pada);

    // --- CSR ptr build: single kernel (internal device barrier) ---
    scan_kernel<<<nscan, SCAN_B, 0, stream>>>(packed, csr_ptr, cursor, dinv,
                                              partial, counter, N, E, nscan);

    // --- CSR fill (standalone: small LDS, full occupancy) ---
    fill_kernel<<<ncc, TB, 0, stream>>>(row, col, ew, dinv, cursor, csr_edge, E);

    dim3 ggrid(MP / 128, HF / 128);   // (391, 2)

    // --- layer 1 ---
    gemm_kernel<<<ggrid, TB, 0, stream>>>(xbf, W1t, bufh, F_IN);
    agg_kernel<0><<<((size_t)N * 64 + TB - 1) / TB, TB, 0, stream>>>(
        bufh, csr_ptr, csr_edge, dinv, b1, g1, be1, m1, v1, bufa, nullptr, nullptr, N);

    // --- layer 2 ---
    gemm_kernel<<<ggrid, TB, 0, stream>>>(bufa, W2t, bufh, HF);
    agg_kernel<1><<<((size_t)N * 64 + TB - 1) / TB, TB, 0, stream>>>(
        bufh, csr_ptr, csr_edge, dinv, b2, g2, be2, m2, v2, nullptr, W3, h3, N);

    // --- final 2-feature aggregation ---
    out_kernel<<<(N + TB - 1) / TB, TB, 0, stream>>>(h3, csr_ptr, csr_edge, dinv, b3, outf, N);
}